// Round 4
// baseline (1739.927 us; speedup 1.0000x reference)
//
#include <hip/hip_runtime.h>
#include <math.h>

#pragma clang fp contract(off)

// Problem constants (match reference)
#define PNUM 136500      // sum of f*f
#define BNUM 16
#define TOPK 5000
#define CAP 8192         // candidate capacity per image (power of 2 for bitonic)
#define NBUCK 65536
#define NWORDS 79        // ceil(5000/64)
#define TRIW 204800      // padded triangular words per image (64 * sum ceil_even(79-t))
#define MASK_PER_IMG ((size_t)TRIW * 8)   // 1,638,400 B

// Workspace layout (bytes). Boxes live at the front; hist/cut/gcnt/keys are
// DEAD after k_sortdecode, so the mask region overlaps them.
#define OFF_SC    ((size_t)0)
#define OFF_X1    (OFF_SC + 320000)
#define OFF_Y1    (OFF_X1 + 320000)
#define OFF_X2    (OFF_Y1 + 320000)
#define OFF_Y2    (OFF_X2 + 320000)
#define OFF_AREA  (OFF_Y2 + 320000)       // ends at 1,920,000
#define OFF_MASK  ((size_t)1920000)
#define OFF_HIST  ((size_t)1920000)       // overlaps mask (dead before k_mask)
#define OFF_CUT   (OFF_HIST + 4194304)
#define OFF_GCNT  (OFF_CUT + 64)
#define OFF_KEYS  (OFF_GCNT + 64)         // 1,048,576 B -> ends 7,163,008

__device__ __forceinline__ unsigned f2ord(float f) {
    unsigned u = __float_as_uint(f);
    return (u & 0x80000000u) ? ~u : (u | 0x80000000u);
}
__device__ __forceinline__ float ord2f(unsigned o) {
    unsigned u = (o & 0x80000000u) ? (o ^ 0x80000000u) : ~o;
    return __uint_as_float(u);
}
// padded row stride (words) of 64-row block t; even => slab is 1024B-multiple
__device__ __forceinline__ int spad(int t) { int s = NWORDS - t; return s + (s & 1); }
// word offset of block t's slab within an image's padded triangular mask
__device__ __forceinline__ int tri_base_pad(int t) {
    int A = NWORDS - t;                       // 79-t
    int S = A * (A + 1) / 2 + ((A + 1) >> 1); // sum_{a=1..A} ceil_even(a)
    return 64 * (3200 - S);                   // 3200 = S(79)
}
// async global->LDS DMA, 16B per lane, wave-uniform LDS base (HW adds lane*16)
__device__ __forceinline__ void async_cp16(const void* g, void* l) {
    __builtin_amdgcn_global_load_lds(
        (const __attribute__((address_space(1))) unsigned*)g,
        (__attribute__((address_space(3))) unsigned*)l, 16, 0, 0);
}

// K1: per-image histogram of score-order top 16 bits
__global__ void k_hist(const float* __restrict__ conf, unsigned* __restrict__ hist) {
    int p = blockIdx.x * 256 + threadIdx.x;
    int img = blockIdx.y;
    if (p >= PNUM) return;
    float s = conf[((size_t)img * PNUM + p) * 2 + 1];
    float m = (s > 0.01f) ? s : -1.0f;
    unsigned o = f2ord(m);
    atomicAdd(&hist[(size_t)img * NBUCK + (o >> 16)], 1u);
}

// K2: find cutoff bucket so that count(bucket >= cut) >= TOPK
__global__ void __launch_bounds__(1024) k_cutoff(const unsigned* __restrict__ hist,
                                                 unsigned* __restrict__ cut) {
    __shared__ unsigned csum[1024];
    int img = blockIdx.x;
    int t = threadIdx.x;
    const unsigned* h = hist + (size_t)img * NBUCK;
    unsigned s = 0;
    for (int b = 0; b < 64; ++b) s += h[t * 64 + b];
    csum[t] = s;
    __syncthreads();
    if (t == 0) {
        unsigned acc = 0, before = 0;
        int c = -1;
        for (int cc = 1023; cc >= 512; --cc) {
            if (acc + csum[cc] >= (unsigned)TOPK) { c = cc; before = acc; break; }
            acc += csum[cc];
        }
        unsigned cutb = 32768u;
        if (c >= 0) {
            unsigned s2 = before;
            cutb = (unsigned)c * 64u;
            for (int b = c * 64 + 63; b >= c * 64; --b) {
                s2 += h[b];
                if (s2 >= (unsigned)TOPK) { cutb = (unsigned)b; break; }
            }
        }
        cut[img] = cutb;
    }
}

// K3: gather candidate keys (ord<<32)|~p for buckets >= cutoff
__global__ void k_gather(const float* __restrict__ conf, const unsigned* __restrict__ cut,
                         unsigned* __restrict__ gcnt, unsigned long long* __restrict__ keys) {
    int p = blockIdx.x * 256 + threadIdx.x;
    int img = blockIdx.y;
    if (p >= PNUM) return;
    float s = conf[((size_t)img * PNUM + p) * 2 + 1];
    if (!(s > 0.01f)) return;
    unsigned o = f2ord(s);
    if ((o >> 16) < cut[img]) return;
    unsigned pos = atomicAdd(&gcnt[img], 1u);
    if (pos < (unsigned)CAP) {
        keys[(size_t)img * CAP + pos] =
            ((unsigned long long)o << 32) | (unsigned)(~(unsigned)p);
    }
}

// K4: per-image bitonic sort (descending) of up to CAP keys; decode top-5000 boxes
__global__ void __launch_bounds__(1024) k_sortdecode(
        const unsigned long long* __restrict__ keys, const unsigned* __restrict__ gcnt,
        const float* __restrict__ loc, const float* __restrict__ pri,
        float* __restrict__ SC, float* __restrict__ X1, float* __restrict__ Y1,
        float* __restrict__ X2, float* __restrict__ Y2, float* __restrict__ AREA) {
    __shared__ unsigned long long sk[CAP];
    int img = blockIdx.x;
    int tid = threadIdx.x;
    int N = (int)min(gcnt[img], (unsigned)CAP);
    for (int i = tid; i < CAP; i += 1024)
        sk[i] = (i < N) ? keys[(size_t)img * CAP + i] : 0ull;
    __syncthreads();
    for (int k = 2; k <= CAP; k <<= 1) {
        for (int j = k >> 1; j > 0; j >>= 1) {
            for (int i = tid; i < CAP; i += 1024) {
                int p2 = i ^ j;
                if (p2 > i) {
                    unsigned long long a = sk[i], b = sk[p2];
                    bool descBlock = ((i & k) == 0);
                    bool doSwap = descBlock ? (a < b) : (a > b);
                    if (doSwap) { sk[i] = b; sk[p2] = a; }
                }
            }
            __syncthreads();
        }
    }
    for (int r = tid; r < TOPK; r += 1024) {
        unsigned long long key = sk[r];
        size_t o = (size_t)img * TOPK + r;
        if (key != 0ull) {
            unsigned ordv = (unsigned)(key >> 32);
            float s = ord2f(ordv);
            unsigned p = ~(unsigned)(key & 0xFFFFFFFFull);
            const float* lp = loc + ((size_t)img * PNUM + p) * 4;
            const float* pp = pri + (size_t)p * 4;
            float lx = lp[0], ly = lp[1], lw = lp[2], lh = lp[3];
            float px = pp[0], py = pp[1], pw = pp[2], ph = pp[3];
            float cx = px + (lx * 0.1f) * pw;
            float cy = py + (ly * 0.1f) * ph;
            float w = pw * expf(lw * 0.2f);
            float h = ph * expf(lh * 0.2f);
            float x1 = cx - w * 0.5f;
            float y1 = cy - h * 0.5f;
            float x2 = x1 + w;
            float y2 = y1 + h;
            SC[o] = s; X1[o] = x1; Y1[o] = y1; X2[o] = x2; Y2[o] = y2;
            AREA[o] = (x2 - x1) * (y2 - y1);
        } else {
            SC[o] = -1.0f; X1[o] = 0.f; Y1[o] = 0.f; X2[o] = 0.f; Y2[o] = 0.f;
            AREA[o] = 0.f;
        }
    }
}

// K5a: padded-triangular suppression mask. Row i (block t=i>>6) stores words
// w in [t,79) at g*TRIW + tri_base_pad(t) + (i&63)*spad(t) + (w-t).
// Bit jj of word w = 1 iff row i (valid) suppresses j=w*64+jj (j>i, iou>0.3).
__global__ void __launch_bounds__(256) k_mask(
        const float* __restrict__ SC, const float* __restrict__ X1,
        const float* __restrict__ Y1, const float* __restrict__ X2,
        const float* __restrict__ Y2, const float* __restrict__ AREA,
        unsigned long long* __restrict__ mask, int img0) {
    int g = blockIdx.z;
    int cb = blockIdx.y;
    int bx = blockIdx.x;
    if ((cb + 1) * 64 <= bx * 256) return;   // whole block strictly sub-diagonal
    __shared__ float cx1[64], cy1[64], cx2[64], cy2[64], car[64];
    int img = img0 + g;
    int i = bx * 256 + threadIdx.x;
    int t = threadIdx.x;
    size_t ib = (size_t)img * TOPK;
    if (t < 64) {
        int j = cb * 64 + t;
        if (j < TOPK) {
            cx1[t] = X1[ib + j]; cy1[t] = Y1[ib + j];
            cx2[t] = X2[ib + j]; cy2[t] = Y2[ib + j];
            car[t] = AREA[ib + j];
        } else {
            cx1[t] = 0.f; cy1[t] = 0.f; cx2[t] = 0.f; cy2[t] = 0.f; car[t] = 0.f;
        }
    }
    __syncthreads();
    if (i >= TOPK) return;
    int ti = i >> 6;
    if (cb < ti) return;                     // sub-diagonal word: not stored
    unsigned long long w = 0;
    float vi = SC[ib + i];
    if (vi > 0.01f) {
        float rx1 = X1[ib + i], ry1 = Y1[ib + i];
        float rx2 = X2[ib + i], ry2 = Y2[ib + i];
        float ra = AREA[ib + i];
        #pragma unroll 8
        for (int jj = 0; jj < 64; ++jj) {
            int j = cb * 64 + jj;
            if (j <= i || j >= TOPK) continue;
            float iw = fmaxf(fminf(rx2, cx2[jj]) - fmaxf(rx1, cx1[jj]), 0.0f);
            float ih = fmaxf(fminf(ry2, cy2[jj]) - fmaxf(ry1, cy1[jj]), 0.0f);
            float inter = iw * ih;
            float iou = inter / (car[jj] + ra - inter);  // (area_j + area_i) - inter
            if (iou > 0.3f) w |= (1ull << jj);
        }
    }
    mask[(size_t)g * TRIW + (size_t)tri_base_pad(ti)
         + (size_t)(i & 63) * spad(ti) + (cb - ti)] = w;
}

// K5b: blocked greedy scan. Wave 0: skip-iterate resolve + apply (lane l owns
// removed-words l and 64+l in registers). Waves 1-3: async-DMA double-buffer
// prefetch of the next block's slab via global_load_lds. One block per image.
__global__ void __launch_bounds__(256) k_scan3(
        const float* __restrict__ SC, const float* __restrict__ X1,
        const float* __restrict__ Y1, const float* __restrict__ X2,
        const float* __restrict__ Y2,
        const unsigned long long* __restrict__ mask, float* __restrict__ out, int img0) {
    __shared__ unsigned long long bufA[64 * 80];   // 40960 B (max slab, t=0)
    __shared__ unsigned long long bufB[64 * 80];
    __shared__ unsigned long long keepw[80];
    __shared__ unsigned pfx[80];
    int g = blockIdx.x;
    int img = img0 + g;
    int tid = threadIdx.x;
    int l = tid & 63;
    int wid = tid >> 6;
    size_t ib = (size_t)img * TOPK;
    const float* sc = SC + ib;
    const unsigned long long* mimg = mask + (size_t)g * TRIW;

    // wave-0 lane l owns removed-words l (rem0) and 64+l (rem1, l<15)
    unsigned long long rem0 = ~0ull, rem1 = ~0ull;
    if (wid == 0) {
        for (int w = 0; w < NWORDS; ++w) {
            int row = w * 64 + l;
            bool valid = (row < TOPK) && (sc[row] > 0.01f);
            unsigned long long b = __ballot(valid);
            if (l == w) rem0 = ~b;
            if (l == w - 64) rem1 = ~b;
        }
    } else {
        // prefetch slab 0 into bufA (40 KiB = 40 units of 1 KiB)
        const char* src = (const char*)mimg;
        char* dst = (char*)bufA;
        int units = (spad(0) * 512) >> 10;
        for (int u = wid - 1; u < units; u += 3)
            async_cp16(src + (size_t)u * 1024 + (size_t)l * 16, dst + u * 1024);
    }
    __syncthreads();

    for (int t = 0; t < NWORDS; ++t) {
        unsigned long long* cur = (t & 1) ? bufB : bufA;
        int sp = spad(t);
        if (wid != 0) {
            if (t + 1 < NWORDS) {
                unsigned long long* nxt = (t & 1) ? bufA : bufB;
                const char* src = (const char*)(mimg + tri_base_pad(t + 1));
                char* dst = (char*)nxt;
                int units = (spad(t + 1) * 512) >> 10;
                for (int u = wid - 1; u < units; u += 3)
                    async_cp16(src + (size_t)u * 1024 + (size_t)l * 16, dst + u * 1024);
            }
        } else {
            // resolve block t: serial greedy over set bits (uniform across wave)
            unsigned long long diag = cur[(size_t)l * sp];   // row l's diagonal word
            unsigned long long remT = (t < 64) ? __shfl(rem0, t, 64)
                                               : __shfl(rem1, t - 64, 64);
            unsigned long long curm = ~remT;
            unsigned long long keepm = 0;
            while (curm) {
                int i = __builtin_ctzll(curm);
                unsigned long long ri = __shfl(diag, i, 64);
                keepm |= (1ull << i);
                curm &= ~(ri | (1ull << i));
            }
            if (l == 0) keepw[t] = keepm;
            // apply alive rows' future-mask words to owned rem words
            bool p0 = (l >= t);
            int o0 = p0 ? (l - t) : 0;
            bool p1 = (l < 15) && (64 + l >= t);
            int o1 = p1 ? (64 + l - t) : 0;
            unsigned long long mm = keepm;
            while (mm) {
                int b = __builtin_ctzll(mm);
                mm &= mm - 1;
                const unsigned long long* row = cur + (size_t)b * sp;
                unsigned long long v0 = row[o0];
                unsigned long long v1 = row[o1];
                if (p0) rem0 |= v0;
                if (p1) rem1 |= v1;
            }
        }
        __syncthreads();   // drains DMA (slab t+1 ready), publishes keepw[t]
    }

    if (tid == 0) {
        unsigned acc = 0;
        for (int w = 0; w < NWORDS; ++w) { pfx[w] = acc; acc += (unsigned)__popcll(keepw[w]); }
    }
    __syncthreads();

    const float* x1 = X1 + ib; const float* y1 = Y1 + ib;
    const float* x2 = X2 + ib; const float* y2 = Y2 + ib;
    float* op = out + (((size_t)img * 2) + 1) * TOPK * 5;
    for (int w = wid; w < NWORDS; w += 4) {
        unsigned long long kw = keepw[w];
        if (!kw) continue;
        int row = w * 64 + l;
        if ((kw >> l) & 1ull) {
            int rank = (int)pfx[w] + (int)__popcll(kw & ((1ull << l) - 1ull));
            float* r = op + (size_t)rank * 5;
            r[0] = sc[row]; r[1] = x1[row]; r[2] = y1[row];
            r[3] = x2[row]; r[4] = y2[row];
        }
    }
}

extern "C" void kernel_launch(void* const* d_in, const int* in_sizes, int n_in,
                              void* d_out, int out_size, void* d_ws, size_t ws_size,
                              hipStream_t stream) {
    (void)in_sizes; (void)n_in;
    const float* loc  = (const float*)d_in[0];   // (16, 136500, 4)
    const float* conf = (const float*)d_in[1];   // (16*136500, 2)
    const float* pri  = (const float*)d_in[2];   // (136500, 4)
    float* out = (float*)d_out;                  // (16, 2, 5000, 5)
    char* ws = (char*)d_ws;

    float* SC   = (float*)(ws + OFF_SC);
    float* X1   = (float*)(ws + OFF_X1);
    float* Y1   = (float*)(ws + OFF_Y1);
    float* X2   = (float*)(ws + OFF_X2);
    float* Y2   = (float*)(ws + OFF_Y2);
    float* AREA = (float*)(ws + OFF_AREA);
    unsigned* hist = (unsigned*)(ws + OFF_HIST);
    unsigned* cut  = (unsigned*)(ws + OFF_CUT);
    unsigned* gcnt = (unsigned*)(ws + OFF_GCNT);
    unsigned long long* keys = (unsigned long long*)(ws + OFF_KEYS);
    unsigned long long* mask = (unsigned long long*)(ws + OFF_MASK);

    hipMemsetAsync(d_out, 0, (size_t)out_size * sizeof(float), stream);
    hipMemsetAsync(ws + OFF_HIST, 0, 4194304 + 128, stream);  // hist + cut + gcnt

    dim3 gb((PNUM + 255) / 256, BNUM);
    k_hist<<<gb, 256, 0, stream>>>(conf, hist);
    k_cutoff<<<BNUM, 1024, 0, stream>>>(hist, cut);
    k_gather<<<gb, 256, 0, stream>>>(conf, cut, gcnt, keys);
    k_sortdecode<<<BNUM, 1024, 0, stream>>>(keys, gcnt, loc, pri, SC, X1, Y1, X2, Y2, AREA);
    // hist/keys region now dead; mask may overwrite it.

    size_t avail = (ws_size > OFF_MASK) ? ws_size - OFF_MASK : 0;
    int gmax = (int)(avail / MASK_PER_IMG);
    if (gmax < 1) gmax = 1;
    if (gmax > BNUM) gmax = BNUM;
    int passes = (BNUM + gmax - 1) / gmax;
    int geach = (BNUM + passes - 1) / passes;   // even split across passes
    for (int i0 = 0; i0 < BNUM; i0 += geach) {
        int G = (BNUM - i0 < geach) ? (BNUM - i0) : geach;
        dim3 mg((TOPK + 255) / 256, NWORDS, G);
        k_mask<<<mg, 256, 0, stream>>>(SC, X1, Y1, X2, Y2, AREA, mask, i0);
        k_scan3<<<G, 256, 0, stream>>>(SC, X1, Y1, X2, Y2, mask, out, i0);
    }
}

// Round 5
// 1146.466 us; speedup vs baseline: 1.5176x; 1.5176x over previous
//
#include <hip/hip_runtime.h>
#include <math.h>

#pragma clang fp contract(off)

// Problem constants (match reference)
#define PNUM 136500      // sum of f*f
#define BNUM 16
#define TOPK 5000
#define CAP 8192         // candidate capacity per image (power of 2 for bitonic)
#define NBUCK 65536
#define NWORDS 79        // ceil(5000/64)
#define TRIW 204800      // padded triangular words per image
#define MASK_PER_IMG ((size_t)TRIW * 8)   // 1,638,400 B

// Workspace layout (bytes). Boxes live at the front; hist/cut/gcnt/keys are
// DEAD after k_sortdecode, so the mask region overlaps them.
#define OFF_SC    ((size_t)0)
#define OFF_X1    (OFF_SC + 320000)
#define OFF_Y1    (OFF_X1 + 320000)
#define OFF_X2    (OFF_Y1 + 320000)
#define OFF_Y2    (OFF_X2 + 320000)
#define OFF_AREA  (OFF_Y2 + 320000)       // ends at 1,920,000
#define OFF_MASK  ((size_t)1920000)
#define OFF_HIST  ((size_t)1920000)       // overlaps mask (dead before k_mask)
#define OFF_CUT   (OFF_HIST + 4194304)
#define OFF_GCNT  (OFF_CUT + 64)
#define OFF_KEYS  (OFF_GCNT + 64)         // 1,048,576 B -> ends 7,163,008

__device__ __forceinline__ unsigned f2ord(float f) {
    unsigned u = __float_as_uint(f);
    return (u & 0x80000000u) ? ~u : (u | 0x80000000u);
}
__device__ __forceinline__ float ord2f(unsigned o) {
    unsigned u = (o & 0x80000000u) ? (o ^ 0x80000000u) : ~o;
    return __uint_as_float(u);
}
// padded row stride (words) of 64-row block t (even)
__device__ __forceinline__ int spad(int t) { int s = NWORDS - t; return s + (s & 1); }
// word offset of block t's slab within an image's padded triangular mask
__device__ __forceinline__ int tri_base_pad(int t) {
    int A = NWORDS - t;                       // 79-t
    int S = A * (A + 1) / 2 + ((A + 1) >> 1); // sum_{a=1..A} ceil_even(a)
    return 64 * (3200 - S);                   // 3200 = S(79)
}

// K1: per-image histogram of score-order top 16 bits
__global__ void k_hist(const float* __restrict__ conf, unsigned* __restrict__ hist) {
    int p = blockIdx.x * 256 + threadIdx.x;
    int img = blockIdx.y;
    if (p >= PNUM) return;
    float s = conf[((size_t)img * PNUM + p) * 2 + 1];
    float m = (s > 0.01f) ? s : -1.0f;
    unsigned o = f2ord(m);
    atomicAdd(&hist[(size_t)img * NBUCK + (o >> 16)], 1u);
}

// K2: find cutoff bucket so that count(bucket >= cut) >= TOPK
__global__ void __launch_bounds__(1024) k_cutoff(const unsigned* __restrict__ hist,
                                                 unsigned* __restrict__ cut) {
    __shared__ unsigned csum[1024];
    int img = blockIdx.x;
    int t = threadIdx.x;
    const unsigned* h = hist + (size_t)img * NBUCK;
    unsigned s = 0;
    for (int b = 0; b < 64; ++b) s += h[t * 64 + b];
    csum[t] = s;
    __syncthreads();
    if (t == 0) {
        unsigned acc = 0, before = 0;
        int c = -1;
        for (int cc = 1023; cc >= 512; --cc) {
            if (acc + csum[cc] >= (unsigned)TOPK) { c = cc; before = acc; break; }
            acc += csum[cc];
        }
        unsigned cutb = 32768u;
        if (c >= 0) {
            unsigned s2 = before;
            cutb = (unsigned)c * 64u;
            for (int b = c * 64 + 63; b >= c * 64; --b) {
                s2 += h[b];
                if (s2 >= (unsigned)TOPK) { cutb = (unsigned)b; break; }
            }
        }
        cut[img] = cutb;
    }
}

// K3: gather candidate keys (ord<<32)|~p for buckets >= cutoff
__global__ void k_gather(const float* __restrict__ conf, const unsigned* __restrict__ cut,
                         unsigned* __restrict__ gcnt, unsigned long long* __restrict__ keys) {
    int p = blockIdx.x * 256 + threadIdx.x;
    int img = blockIdx.y;
    if (p >= PNUM) return;
    float s = conf[((size_t)img * PNUM + p) * 2 + 1];
    if (!(s > 0.01f)) return;
    unsigned o = f2ord(s);
    if ((o >> 16) < cut[img]) return;
    unsigned pos = atomicAdd(&gcnt[img], 1u);
    if (pos < (unsigned)CAP) {
        keys[(size_t)img * CAP + pos] =
            ((unsigned long long)o << 32) | (unsigned)(~(unsigned)p);
    }
}

// K4: per-image bitonic sort (descending) of up to CAP keys; decode top-5000 boxes
__global__ void __launch_bounds__(1024) k_sortdecode(
        const unsigned long long* __restrict__ keys, const unsigned* __restrict__ gcnt,
        const float* __restrict__ loc, const float* __restrict__ pri,
        float* __restrict__ SC, float* __restrict__ X1, float* __restrict__ Y1,
        float* __restrict__ X2, float* __restrict__ Y2, float* __restrict__ AREA) {
    __shared__ unsigned long long sk[CAP];
    int img = blockIdx.x;
    int tid = threadIdx.x;
    int N = (int)min(gcnt[img], (unsigned)CAP);
    for (int i = tid; i < CAP; i += 1024)
        sk[i] = (i < N) ? keys[(size_t)img * CAP + i] : 0ull;
    __syncthreads();
    for (int k = 2; k <= CAP; k <<= 1) {
        for (int j = k >> 1; j > 0; j >>= 1) {
            for (int i = tid; i < CAP; i += 1024) {
                int p2 = i ^ j;
                if (p2 > i) {
                    unsigned long long a = sk[i], b = sk[p2];
                    bool descBlock = ((i & k) == 0);
                    bool doSwap = descBlock ? (a < b) : (a > b);
                    if (doSwap) { sk[i] = b; sk[p2] = a; }
                }
            }
            __syncthreads();
        }
    }
    for (int r = tid; r < TOPK; r += 1024) {
        unsigned long long key = sk[r];
        size_t o = (size_t)img * TOPK + r;
        if (key != 0ull) {
            unsigned ordv = (unsigned)(key >> 32);
            float s = ord2f(ordv);
            unsigned p = ~(unsigned)(key & 0xFFFFFFFFull);
            const float* lp = loc + ((size_t)img * PNUM + p) * 4;
            const float* pp = pri + (size_t)p * 4;
            float lx = lp[0], ly = lp[1], lw = lp[2], lh = lp[3];
            float px = pp[0], py = pp[1], pw = pp[2], ph = pp[3];
            float cx = px + (lx * 0.1f) * pw;
            float cy = py + (ly * 0.1f) * ph;
            float w = pw * expf(lw * 0.2f);
            float h = ph * expf(lh * 0.2f);
            float x1 = cx - w * 0.5f;
            float y1 = cy - h * 0.5f;
            float x2 = x1 + w;
            float y2 = y1 + h;
            SC[o] = s; X1[o] = x1; Y1[o] = y1; X2[o] = x2; Y2[o] = y2;
            AREA[o] = (x2 - x1) * (y2 - y1);
        } else {
            SC[o] = -1.0f; X1[o] = 0.f; Y1[o] = 0.f; X2[o] = 0.f; Y2[o] = 0.f;
            AREA[o] = 0.f;
        }
    }
}

// K5a: padded-triangular suppression mask. Row i (block t=i>>6) stores words
// w in [t,79) at g*TRIW + tri_base_pad(t) + (i&63)*spad(t) + (w-t).
// Bit jj of word w = 1 iff row i (valid) suppresses j=w*64+jj (j>i, iou>0.3).
__global__ void __launch_bounds__(256) k_mask(
        const float* __restrict__ SC, const float* __restrict__ X1,
        const float* __restrict__ Y1, const float* __restrict__ X2,
        const float* __restrict__ Y2, const float* __restrict__ AREA,
        unsigned long long* __restrict__ mask, int img0) {
    int g = blockIdx.z;
    int cb = blockIdx.y;
    int bx = blockIdx.x;
    if ((cb + 1) * 64 <= bx * 256) return;   // whole block strictly sub-diagonal
    __shared__ float cx1[64], cy1[64], cx2[64], cy2[64], car[64];
    int img = img0 + g;
    int i = bx * 256 + threadIdx.x;
    int t = threadIdx.x;
    size_t ib = (size_t)img * TOPK;
    if (t < 64) {
        int j = cb * 64 + t;
        if (j < TOPK) {
            cx1[t] = X1[ib + j]; cy1[t] = Y1[ib + j];
            cx2[t] = X2[ib + j]; cy2[t] = Y2[ib + j];
            car[t] = AREA[ib + j];
        } else {
            cx1[t] = 0.f; cy1[t] = 0.f; cx2[t] = 0.f; cy2[t] = 0.f; car[t] = 0.f;
        }
    }
    __syncthreads();
    if (i >= TOPK) return;
    int ti = i >> 6;
    if (cb < ti) return;                     // sub-diagonal word: not stored
    unsigned long long w = 0;
    float vi = SC[ib + i];
    if (vi > 0.01f) {
        float rx1 = X1[ib + i], ry1 = Y1[ib + i];
        float rx2 = X2[ib + i], ry2 = Y2[ib + i];
        float ra = AREA[ib + i];
        #pragma unroll 8
        for (int jj = 0; jj < 64; ++jj) {
            int j = cb * 64 + jj;
            if (j <= i || j >= TOPK) continue;
            float iw = fmaxf(fminf(rx2, cx2[jj]) - fmaxf(rx1, cx1[jj]), 0.0f);
            float ih = fmaxf(fminf(ry2, cy2[jj]) - fmaxf(ry1, cy1[jj]), 0.0f);
            float inter = iw * ih;
            float iou = inter / (car[jj] + ra - inter);  // (area_j + area_i) - inter
            if (iou > 0.3f) w |= (1ull << jj);
        }
    }
    mask[(size_t)g * TRIW + (size_t)tri_base_pad(ti)
         + (size_t)(i & 63) * spad(ti) + (cb - ti)] = w;
}

// K5b: blocked greedy scan, fully cooperative. Per tile t:
//  A) all 256 threads preload the slab into VGPRs (coalesced, no LDS staging)
//  B) wave 0 folds previous tile's partial ORs into register-resident rem,
//     resolves tile t via sparse ballot fast-path + short shfl chain
//  C) all threads fold their kept-row values -> prem[wave][col] in LDS
// One block per image.
__global__ void __launch_bounds__(256) k_scan4(
        const float* __restrict__ SC, const float* __restrict__ X1,
        const float* __restrict__ Y1, const float* __restrict__ X2,
        const float* __restrict__ Y2,
        const unsigned long long* __restrict__ mask, float* __restrict__ out, int img0) {
    __shared__ unsigned long long prem[4][80];
    __shared__ unsigned long long keepw[80];
    __shared__ unsigned pfx[80];
    __shared__ unsigned long long keepm_sh;
    int g = blockIdx.x;
    int img = img0 + g;
    int tid = threadIdx.x;
    int l = tid & 63;
    int wid = tid >> 6;
    size_t ib = (size_t)img * TOPK;
    const float* sc = SC + ib;
    const unsigned long long* mimg = mask + (size_t)g * TRIW;

    // wave-0 lane l owns removed-words l (rem0) and 64+l (rem1, l<15)
    unsigned long long rem0 = ~0ull, rem1 = ~0ull;
    if (wid == 0) {
        for (int w = 0; w < NWORDS; ++w) {
            int row = w * 64 + l;
            bool valid = (row < TOPK) && (sc[row] > 0.01f);
            unsigned long long b = __ballot(valid);
            if (l == w) rem0 = ~b;
            if (l == w - 64) rem1 = ~b;
        }
    }
    __syncthreads();

    for (int t = 0; t < NWORDS; ++t) {
        int s = NWORDS - t;
        int sp = spad(t);
        const unsigned long long* base = mimg + tri_base_pad(t);
        // A: preload. thread (wid,l): rows wid*16..+15, cols l and 64+l.
        bool a0 = (l < s);
        bool a1 = (64 + l < s);
        unsigned long long diag = 0;
        if (wid == 0) diag = base[(size_t)l * sp];
        unsigned long long v0[16], v1[16];
        #pragma unroll
        for (int r = 0; r < 16; ++r) {
            int b = wid * 16 + r;
            v0[r] = a0 ? base[(size_t)b * sp + l] : 0ull;
            v1[r] = a1 ? base[(size_t)b * sp + 64 + l] : 0ull;
        }
        // B: wave 0 folds prev prem, then resolves tile t
        if (wid == 0) {
            if (t > 0) {
                int tp = t - 1;
                int c0 = l - tp;
                if (c0 >= 0)
                    rem0 |= prem[0][c0] | prem[1][c0] | prem[2][c0] | prem[3][c0];
                if (l < 15) {
                    int c1 = 64 + l - tp;
                    if (c1 >= 0)
                        rem1 |= prem[0][c1] | prem[1][c1] | prem[2][c1] | prem[3][c1];
                }
            }
            unsigned long long remT = (t < 64) ? __shfl(rem0, t, 64)
                                               : __shfl(rem1, t - 64, 64);
            unsigned long long aliveInit = ~remT;
            bool meAlive = ((aliveInit >> l) & 1ull) != 0ull;
            unsigned long long dEff = diag & aliveInit;
            unsigned long long sup = __ballot(meAlive && (dEff != 0ull));
            unsigned long long removed = remT;
            while (sup) {                       // usually empty or 1-3 rows
                int i = __builtin_ctzll(sup);
                sup &= sup - 1;
                if (!((removed >> i) & 1ull)) {
                    unsigned long long di = __shfl(diag, i, 64);
                    removed |= di;              // di only has bits > i
                    sup &= ~di;
                }
            }
            unsigned long long keepm = ~removed;
            if (l == 0) { keepw[t] = keepm; keepm_sh = keepm; }
        }
        __syncthreads();
        // C: fold kept rows into per-wave partials
        unsigned long long keepm = keepm_sh;
        unsigned long long acc0 = 0, acc1 = 0;
        #pragma unroll
        for (int r = 0; r < 16; ++r) {
            int b = wid * 16 + r;
            if ((keepm >> b) & 1ull) { acc0 |= v0[r]; acc1 |= v1[r]; }
        }
        if (a0) prem[wid][l] = acc0;
        if (a1) prem[wid][64 + l] = acc1;
        __syncthreads();
    }

    if (tid == 0) {
        unsigned acc = 0;
        for (int w = 0; w < NWORDS; ++w) { pfx[w] = acc; acc += (unsigned)__popcll(keepw[w]); }
    }
    __syncthreads();

    const float* x1 = X1 + ib; const float* y1 = Y1 + ib;
    const float* x2 = X2 + ib; const float* y2 = Y2 + ib;
    float* op = out + (((size_t)img * 2) + 1) * TOPK * 5;
    for (int w = wid; w < NWORDS; w += 4) {
        unsigned long long kw = keepw[w];
        if (!kw) continue;
        int row = w * 64 + l;
        if ((kw >> l) & 1ull) {
            int rank = (int)pfx[w] + (int)__popcll(kw & ((1ull << l) - 1ull));
            float* r = op + (size_t)rank * 5;
            r[0] = sc[row]; r[1] = x1[row]; r[2] = y1[row];
            r[3] = x2[row]; r[4] = y2[row];
        }
    }
}

extern "C" void kernel_launch(void* const* d_in, const int* in_sizes, int n_in,
                              void* d_out, int out_size, void* d_ws, size_t ws_size,
                              hipStream_t stream) {
    (void)in_sizes; (void)n_in;
    const float* loc  = (const float*)d_in[0];   // (16, 136500, 4)
    const float* conf = (const float*)d_in[1];   // (16*136500, 2)
    const float* pri  = (const float*)d_in[2];   // (136500, 4)
    float* out = (float*)d_out;                  // (16, 2, 5000, 5)
    char* ws = (char*)d_ws;

    float* SC   = (float*)(ws + OFF_SC);
    float* X1   = (float*)(ws + OFF_X1);
    float* Y1   = (float*)(ws + OFF_Y1);
    float* X2   = (float*)(ws + OFF_X2);
    float* Y2   = (float*)(ws + OFF_Y2);
    float* AREA = (float*)(ws + OFF_AREA);
    unsigned* hist = (unsigned*)(ws + OFF_HIST);
    unsigned* cut  = (unsigned*)(ws + OFF_CUT);
    unsigned* gcnt = (unsigned*)(ws + OFF_GCNT);
    unsigned long long* keys = (unsigned long long*)(ws + OFF_KEYS);
    unsigned long long* mask = (unsigned long long*)(ws + OFF_MASK);

    hipMemsetAsync(d_out, 0, (size_t)out_size * sizeof(float), stream);
    hipMemsetAsync(ws + OFF_HIST, 0, 4194304 + 128, stream);  // hist + cut + gcnt

    dim3 gb((PNUM + 255) / 256, BNUM);
    k_hist<<<gb, 256, 0, stream>>>(conf, hist);
    k_cutoff<<<BNUM, 1024, 0, stream>>>(hist, cut);
    k_gather<<<gb, 256, 0, stream>>>(conf, cut, gcnt, keys);
    k_sortdecode<<<BNUM, 1024, 0, stream>>>(keys, gcnt, loc, pri, SC, X1, Y1, X2, Y2, AREA);
    // hist/keys region now dead; mask may overwrite it.

    size_t avail = (ws_size > OFF_MASK) ? ws_size - OFF_MASK : 0;
    int gmax = (int)(avail / MASK_PER_IMG);
    if (gmax < 1) gmax = 1;
    if (gmax > BNUM) gmax = BNUM;
    int passes = (BNUM + gmax - 1) / gmax;
    int geach = (BNUM + passes - 1) / passes;   // even split across passes
    for (int i0 = 0; i0 < BNUM; i0 += geach) {
        int G = (BNUM - i0 < geach) ? (BNUM - i0) : geach;
        dim3 mg((TOPK + 255) / 256, NWORDS, G);
        k_mask<<<mg, 256, 0, stream>>>(SC, X1, Y1, X2, Y2, AREA, mask, i0);
        k_scan4<<<G, 256, 0, stream>>>(SC, X1, Y1, X2, Y2, mask, out, i0);
    }
}

// Round 6
// 743.474 us; speedup vs baseline: 2.3403x; 1.5420x over previous
//
#include <hip/hip_runtime.h>
#include <math.h>

#pragma clang fp contract(off)

// Problem constants (match reference)
#define PNUM 136500      // sum of f*f
#define HPNUM 68250      // PNUM/2 (exact)
#define BNUM 16
#define TOPK 5000
#define CAP 8192         // candidate capacity per image (power of 2 for bitonic)
#define NBUCK 65536
#define NWORDS 79        // ceil(5000/64)
#define TRIW 204800      // padded triangular words per image
#define MASK_PER_IMG ((size_t)TRIW * 8)   // 1,638,400 B
#define GSTRIDE 32       // gcnt padding: 32 u32 = 128 B per image

// Workspace layout (bytes). Boxes live at the front; hist/cut/gcnt/keys are
// DEAD after k_sortdecode, so the mask region overlaps them.
#define OFF_SC    ((size_t)0)
#define OFF_X1    (OFF_SC + 320000)
#define OFF_Y1    (OFF_X1 + 320000)
#define OFF_X2    (OFF_Y1 + 320000)
#define OFF_Y2    (OFF_X2 + 320000)
#define OFF_AREA  (OFF_Y2 + 320000)       // ends at 1,920,000
#define OFF_MASK  ((size_t)1920000)
#define OFF_HIST  ((size_t)1920000)       // overlaps mask (dead before k_mask)
#define OFF_CUT   (OFF_HIST + 4194304)
#define OFF_GCNT  (OFF_CUT + 64)
#define OFF_KEYS  (OFF_GCNT + 2048)

__device__ __forceinline__ unsigned f2ord(float f) {
    unsigned u = __float_as_uint(f);
    return (u & 0x80000000u) ? ~u : (u | 0x80000000u);
}
__device__ __forceinline__ float ord2f(unsigned o) {
    unsigned u = (o & 0x80000000u) ? (o ^ 0x80000000u) : ~o;
    return __uint_as_float(u);
}
// padded row stride (words) of 64-row block t (even)
__device__ __forceinline__ int spad(int t) { int s = NWORDS - t; return s + (s & 1); }
// word offset of block t's slab within an image's padded triangular mask
__device__ __forceinline__ int tri_base_pad(int t) {
    int A = NWORDS - t;                       // 79-t
    int S = A * (A + 1) / 2 + ((A + 1) >> 1); // sum_{a=1..A} ceil_even(a)
    return 64 * (3200 - S);                   // 3200 = S(79)
}

// K1: per-image histogram of score-order top 16 bits. 2 priors/thread via
// float4; invalid (<=0.01) entries are skipped (their bucket 0x407F is below
// 0x8000 and never scanned by k_cutoff).
__global__ void __launch_bounds__(256) k_hist(const float* __restrict__ conf,
                                              unsigned* __restrict__ hist) {
    int q = blockIdx.x * 256 + threadIdx.x;
    int img = blockIdx.y;
    if (q >= HPNUM) return;
    float4 v = ((const float4*)(conf + (size_t)img * PNUM * 2))[q];
    unsigned* h = hist + (size_t)img * NBUCK;
    if (v.y > 0.01f) atomicAdd(&h[f2ord(v.y) >> 16], 1u);
    if (v.w > 0.01f) atomicAdd(&h[f2ord(v.w) >> 16], 1u);
}

// K2: find cutoff bucket so that count(bucket >= cut) >= TOPK
__global__ void __launch_bounds__(1024) k_cutoff(const unsigned* __restrict__ hist,
                                                 unsigned* __restrict__ cut) {
    __shared__ unsigned csum[1024];
    int img = blockIdx.x;
    int t = threadIdx.x;
    const unsigned* h = hist + (size_t)img * NBUCK;
    unsigned s = 0;
    for (int b = 0; b < 64; ++b) s += h[t * 64 + b];
    csum[t] = s;
    __syncthreads();
    if (t == 0) {
        unsigned acc = 0, before = 0;
        int c = -1;
        for (int cc = 1023; cc >= 512; --cc) {
            if (acc + csum[cc] >= (unsigned)TOPK) { c = cc; before = acc; break; }
            acc += csum[cc];
        }
        unsigned cutb = 32768u;
        if (c >= 0) {
            unsigned s2 = before;
            cutb = (unsigned)c * 64u;
            for (int b = c * 64 + 63; b >= c * 64; --b) {
                s2 += h[b];
                if (s2 >= (unsigned)TOPK) { cutb = (unsigned)b; break; }
            }
        }
        cut[img] = cutb;
    }
}

// K3: gather candidate keys (ord<<32)|~p for buckets >= cutoff.
// Block-aggregated position allocation: ONE atomicAdd per block to a 128B-
// padded counter. Buffer order is irrelevant (keys get fully sorted).
__global__ void __launch_bounds__(256) k_gather(
        const float* __restrict__ conf, const unsigned* __restrict__ cut,
        unsigned* __restrict__ gcnt, unsigned long long* __restrict__ keys) {
    __shared__ unsigned wbase[4];
    __shared__ unsigned bbase;
    int q = blockIdx.x * 256 + threadIdx.x;
    int img = blockIdx.y;
    int lane = threadIdx.x & 63, wid = threadIdx.x >> 6;
    unsigned cutb = cut[img];
    bool c0 = false, c1 = false;
    unsigned o0 = 0, o1 = 0;
    int p0 = 0, p1 = 0;
    if (q < HPNUM) {
        float4 v = ((const float4*)(conf + (size_t)img * PNUM * 2))[q];
        p0 = 2 * q; p1 = 2 * q + 1;
        if (v.y > 0.01f) { o0 = f2ord(v.y); c0 = (o0 >> 16) >= cutb; }
        if (v.w > 0.01f) { o1 = f2ord(v.w); c1 = (o1 >> 16) >= cutb; }
    }
    unsigned long long b0 = __ballot(c0), b1 = __ballot(c1);
    if (lane == 0) wbase[wid] = (unsigned)(__popcll(b0) + __popcll(b1));
    __syncthreads();
    if (threadIdx.x == 0) {
        unsigned t0 = wbase[0], t1 = wbase[1], t2 = wbase[2], t3 = wbase[3];
        unsigned tot = t0 + t1 + t2 + t3;
        unsigned base = tot ? atomicAdd(&gcnt[(size_t)img * GSTRIDE], tot) : 0u;
        bbase = base;
        wbase[0] = 0; wbase[1] = t0; wbase[2] = t0 + t1; wbase[3] = t0 + t1 + t2;
    }
    __syncthreads();
    unsigned mybase = bbase + wbase[wid];
    unsigned long long lt = (lane == 0) ? 0ull : ((1ull << lane) - 1ull);
    if (c0) {
        unsigned pos = mybase + (unsigned)__popcll(b0 & lt);
        if (pos < (unsigned)CAP)
            keys[(size_t)img * CAP + pos] =
                ((unsigned long long)o0 << 32) | (unsigned)(~(unsigned)p0);
    }
    if (c1) {
        unsigned pos = mybase + (unsigned)__popcll(b0) + (unsigned)__popcll(b1 & lt);
        if (pos < (unsigned)CAP)
            keys[(size_t)img * CAP + pos] =
                ((unsigned long long)o1 << 32) | (unsigned)(~(unsigned)p1);
    }
}

// K4: per-image bitonic sort (descending) of up to CAP keys; decode top-5000 boxes
__global__ void __launch_bounds__(1024) k_sortdecode(
        const unsigned long long* __restrict__ keys, const unsigned* __restrict__ gcnt,
        const float* __restrict__ loc, const float* __restrict__ pri,
        float* __restrict__ SC, float* __restrict__ X1, float* __restrict__ Y1,
        float* __restrict__ X2, float* __restrict__ Y2, float* __restrict__ AREA) {
    __shared__ unsigned long long sk[CAP];
    int img = blockIdx.x;
    int tid = threadIdx.x;
    int N = (int)min(gcnt[(size_t)img * GSTRIDE], (unsigned)CAP);
    for (int i = tid; i < CAP; i += 1024)
        sk[i] = (i < N) ? keys[(size_t)img * CAP + i] : 0ull;
    __syncthreads();
    for (int k = 2; k <= CAP; k <<= 1) {
        for (int j = k >> 1; j > 0; j >>= 1) {
            for (int i = tid; i < CAP; i += 1024) {
                int p2 = i ^ j;
                if (p2 > i) {
                    unsigned long long a = sk[i], b = sk[p2];
                    bool descBlock = ((i & k) == 0);
                    bool doSwap = descBlock ? (a < b) : (a > b);
                    if (doSwap) { sk[i] = b; sk[p2] = a; }
                }
            }
            __syncthreads();
        }
    }
    for (int r = tid; r < TOPK; r += 1024) {
        unsigned long long key = sk[r];
        size_t o = (size_t)img * TOPK + r;
        if (key != 0ull) {
            unsigned ordv = (unsigned)(key >> 32);
            float s = ord2f(ordv);
            unsigned p = ~(unsigned)(key & 0xFFFFFFFFull);
            const float* lp = loc + ((size_t)img * PNUM + p) * 4;
            const float* pp = pri + (size_t)p * 4;
            float lx = lp[0], ly = lp[1], lw = lp[2], lh = lp[3];
            float px = pp[0], py = pp[1], pw = pp[2], ph = pp[3];
            float cx = px + (lx * 0.1f) * pw;
            float cy = py + (ly * 0.1f) * ph;
            float w = pw * expf(lw * 0.2f);
            float h = ph * expf(lh * 0.2f);
            float x1 = cx - w * 0.5f;
            float y1 = cy - h * 0.5f;
            float x2 = x1 + w;
            float y2 = y1 + h;
            SC[o] = s; X1[o] = x1; Y1[o] = y1; X2[o] = x2; Y2[o] = y2;
            AREA[o] = (x2 - x1) * (y2 - y1);
        } else {
            SC[o] = -1.0f; X1[o] = 0.f; Y1[o] = 0.f; X2[o] = 0.f; Y2[o] = 0.f;
            AREA[o] = 0.f;
        }
    }
}

// K5a: padded-triangular suppression mask. Row i (block t=i>>6) stores words
// w in [t,79) at g*TRIW + tri_base_pad(t) + (i&63)*spad(t) + (w-t).
// Bit jj of word w = 1 iff row i (valid) suppresses j=w*64+jj (j>i, iou>0.3).
__global__ void __launch_bounds__(256) k_mask(
        const float* __restrict__ SC, const float* __restrict__ X1,
        const float* __restrict__ Y1, const float* __restrict__ X2,
        const float* __restrict__ Y2, const float* __restrict__ AREA,
        unsigned long long* __restrict__ mask, int img0) {
    int g = blockIdx.z;
    int cb = blockIdx.y;
    int bx = blockIdx.x;
    if ((cb + 1) * 64 <= bx * 256) return;   // whole block strictly sub-diagonal
    __shared__ float cx1[64], cy1[64], cx2[64], cy2[64], car[64];
    int img = img0 + g;
    int i = bx * 256 + threadIdx.x;
    int t = threadIdx.x;
    size_t ib = (size_t)img * TOPK;
    if (t < 64) {
        int j = cb * 64 + t;
        if (j < TOPK) {
            cx1[t] = X1[ib + j]; cy1[t] = Y1[ib + j];
            cx2[t] = X2[ib + j]; cy2[t] = Y2[ib + j];
            car[t] = AREA[ib + j];
        } else {
            cx1[t] = 0.f; cy1[t] = 0.f; cx2[t] = 0.f; cy2[t] = 0.f; car[t] = 0.f;
        }
    }
    __syncthreads();
    if (i >= TOPK) return;
    int ti = i >> 6;
    if (cb < ti) return;                     // sub-diagonal word: not stored
    unsigned long long w = 0;
    float vi = SC[ib + i];
    if (vi > 0.01f) {
        float rx1 = X1[ib + i], ry1 = Y1[ib + i];
        float rx2 = X2[ib + i], ry2 = Y2[ib + i];
        float ra = AREA[ib + i];
        #pragma unroll 8
        for (int jj = 0; jj < 64; ++jj) {
            int j = cb * 64 + jj;
            if (j <= i || j >= TOPK) continue;
            float iw = fmaxf(fminf(rx2, cx2[jj]) - fmaxf(rx1, cx1[jj]), 0.0f);
            float ih = fmaxf(fminf(ry2, cy2[jj]) - fmaxf(ry1, cy1[jj]), 0.0f);
            float inter = iw * ih;
            float iou = inter / (car[jj] + ra - inter);  // (area_j + area_i) - inter
            if (iou > 0.3f) w |= (1ull << jj);
        }
    }
    mask[(size_t)g * TRIW + (size_t)tri_base_pad(ti)
         + (size_t)(i & 63) * spad(ti) + (cb - ti)] = w;
}

// K5b: blocked greedy scan, fully cooperative. Per tile t:
//  A) all 256 threads preload the slab into VGPRs (coalesced, no LDS staging)
//  B) wave 0 folds previous tile's partial ORs into register-resident rem,
//     resolves tile t via sparse ballot fast-path + short shfl chain
//  C) all threads fold their kept-row values -> prem[wave][col] in LDS
// One block per image.
__global__ void __launch_bounds__(256) k_scan4(
        const float* __restrict__ SC, const float* __restrict__ X1,
        const float* __restrict__ Y1, const float* __restrict__ X2,
        const float* __restrict__ Y2,
        const unsigned long long* __restrict__ mask, float* __restrict__ out, int img0) {
    __shared__ unsigned long long prem[4][80];
    __shared__ unsigned long long keepw[80];
    __shared__ unsigned pfx[80];
    __shared__ unsigned long long keepm_sh;
    int g = blockIdx.x;
    int img = img0 + g;
    int tid = threadIdx.x;
    int l = tid & 63;
    int wid = tid >> 6;
    size_t ib = (size_t)img * TOPK;
    const float* sc = SC + ib;
    const unsigned long long* mimg = mask + (size_t)g * TRIW;

    // wave-0 lane l owns removed-words l (rem0) and 64+l (rem1, l<15)
    unsigned long long rem0 = ~0ull, rem1 = ~0ull;
    if (wid == 0) {
        for (int w = 0; w < NWORDS; ++w) {
            int row = w * 64 + l;
            bool valid = (row < TOPK) && (sc[row] > 0.01f);
            unsigned long long b = __ballot(valid);
            if (l == w) rem0 = ~b;
            if (l == w - 64) rem1 = ~b;
        }
    }
    __syncthreads();

    for (int t = 0; t < NWORDS; ++t) {
        int s = NWORDS - t;
        int sp = spad(t);
        const unsigned long long* base = mimg + tri_base_pad(t);
        // A: preload. thread (wid,l): rows wid*16..+15, cols l and 64+l.
        bool a0 = (l < s);
        bool a1 = (64 + l < s);
        unsigned long long diag = 0;
        if (wid == 0) diag = base[(size_t)l * sp];
        unsigned long long v0[16], v1[16];
        #pragma unroll
        for (int r = 0; r < 16; ++r) {
            int b = wid * 16 + r;
            v0[r] = a0 ? base[(size_t)b * sp + l] : 0ull;
            v1[r] = a1 ? base[(size_t)b * sp + 64 + l] : 0ull;
        }
        // B: wave 0 folds prev prem, then resolves tile t
        if (wid == 0) {
            if (t > 0) {
                int tp = t - 1;
                int c0 = l - tp;
                if (c0 >= 0)
                    rem0 |= prem[0][c0] | prem[1][c0] | prem[2][c0] | prem[3][c0];
                if (l < 15) {
                    int c1 = 64 + l - tp;
                    if (c1 >= 0)
                        rem1 |= prem[0][c1] | prem[1][c1] | prem[2][c1] | prem[3][c1];
                }
            }
            unsigned long long remT = (t < 64) ? __shfl(rem0, t, 64)
                                               : __shfl(rem1, t - 64, 64);
            unsigned long long aliveInit = ~remT;
            bool meAlive = ((aliveInit >> l) & 1ull) != 0ull;
            unsigned long long dEff = diag & aliveInit;
            unsigned long long sup = __ballot(meAlive && (dEff != 0ull));
            unsigned long long removed = remT;
            while (sup) {                       // usually empty or 1-3 rows
                int i = __builtin_ctzll(sup);
                sup &= sup - 1;
                if (!((removed >> i) & 1ull)) {
                    unsigned long long di = __shfl(diag, i, 64);
                    removed |= di;              // di only has bits > i
                    sup &= ~di;
                }
            }
            unsigned long long keepm = ~removed;
            if (l == 0) { keepw[t] = keepm; keepm_sh = keepm; }
        }
        __syncthreads();
        // C: fold kept rows into per-wave partials
        unsigned long long keepm = keepm_sh;
        unsigned long long acc0 = 0, acc1 = 0;
        #pragma unroll
        for (int r = 0; r < 16; ++r) {
            int b = wid * 16 + r;
            if ((keepm >> b) & 1ull) { acc0 |= v0[r]; acc1 |= v1[r]; }
        }
        if (a0) prem[wid][l] = acc0;
        if (a1) prem[wid][64 + l] = acc1;
        __syncthreads();
    }

    if (tid == 0) {
        unsigned acc = 0;
        for (int w = 0; w < NWORDS; ++w) { pfx[w] = acc; acc += (unsigned)__popcll(keepw[w]); }
    }
    __syncthreads();

    const float* x1 = X1 + ib; const float* y1 = Y1 + ib;
    const float* x2 = X2 + ib; const float* y2 = Y2 + ib;
    float* op = out + (((size_t)img * 2) + 1) * TOPK * 5;
    for (int w = wid; w < NWORDS; w += 4) {
        unsigned long long kw = keepw[w];
        if (!kw) continue;
        int row = w * 64 + l;
        if ((kw >> l) & 1ull) {
            int rank = (int)pfx[w] + (int)__popcll(kw & ((1ull << l) - 1ull));
            float* r = op + (size_t)rank * 5;
            r[0] = sc[row]; r[1] = x1[row]; r[2] = y1[row];
            r[3] = x2[row]; r[4] = y2[row];
        }
    }
}

extern "C" void kernel_launch(void* const* d_in, const int* in_sizes, int n_in,
                              void* d_out, int out_size, void* d_ws, size_t ws_size,
                              hipStream_t stream) {
    (void)in_sizes; (void)n_in;
    const float* loc  = (const float*)d_in[0];   // (16, 136500, 4)
    const float* conf = (const float*)d_in[1];   // (16*136500, 2)
    const float* pri  = (const float*)d_in[2];   // (136500, 4)
    float* out = (float*)d_out;                  // (16, 2, 5000, 5)
    char* ws = (char*)d_ws;

    float* SC   = (float*)(ws + OFF_SC);
    float* X1   = (float*)(ws + OFF_X1);
    float* Y1   = (float*)(ws + OFF_Y1);
    float* X2   = (float*)(ws + OFF_X2);
    float* Y2   = (float*)(ws + OFF_Y2);
    float* AREA = (float*)(ws + OFF_AREA);
    unsigned* hist = (unsigned*)(ws + OFF_HIST);
    unsigned* cut  = (unsigned*)(ws + OFF_CUT);
    unsigned* gcnt = (unsigned*)(ws + OFF_GCNT);
    unsigned long long* keys = (unsigned long long*)(ws + OFF_KEYS);
    unsigned long long* mask = (unsigned long long*)(ws + OFF_MASK);

    hipMemsetAsync(d_out, 0, (size_t)out_size * sizeof(float), stream);
    hipMemsetAsync(ws + OFF_HIST, 0, 4194304 + 64 + 2048, stream); // hist+cut+gcnt

    dim3 gh((HPNUM + 255) / 256, BNUM);
    k_hist<<<gh, 256, 0, stream>>>(conf, hist);
    k_cutoff<<<BNUM, 1024, 0, stream>>>(hist, cut);
    k_gather<<<gh, 256, 0, stream>>>(conf, cut, gcnt, keys);
    k_sortdecode<<<BNUM, 1024, 0, stream>>>(keys, gcnt, loc, pri, SC, X1, Y1, X2, Y2, AREA);
    // hist/keys region now dead; mask may overwrite it.

    size_t avail = (ws_size > OFF_MASK) ? ws_size - OFF_MASK : 0;
    int gmax = (int)(avail / MASK_PER_IMG);
    if (gmax < 1) gmax = 1;
    if (gmax > BNUM) gmax = BNUM;
    int passes = (BNUM + gmax - 1) / gmax;
    int geach = (BNUM + passes - 1) / passes;   // even split across passes
    for (int i0 = 0; i0 < BNUM; i0 += geach) {
        int G = (BNUM - i0 < geach) ? (BNUM - i0) : geach;
        dim3 mg((TOPK + 255) / 256, NWORDS, G);
        k_mask<<<mg, 256, 0, stream>>>(SC, X1, Y1, X2, Y2, AREA, mask, i0);
        k_scan4<<<G, 256, 0, stream>>>(SC, X1, Y1, X2, Y2, mask, out, i0);
    }
}

// Round 7
// 556.769 us; speedup vs baseline: 3.1250x; 1.3353x over previous
//
#include <hip/hip_runtime.h>
#include <math.h>

#pragma clang fp contract(off)

// Problem constants (match reference)
#define PNUM 136500      // sum of f*f
#define HPNUM 68250      // PNUM/2 (exact)
#define BNUM 16
#define TOPK 5000
#define CAP 8192         // candidate capacity per image (power of 2 for bitonic)
#define NB2 1024         // histogram window buckets (covers ord16 of (0.01, 1.0))
#define B2BASE 0xBC00u   // window base: f2ord(0.01)>>16 = 0xBC23 >= 0xBC00
#define NWORDS 79        // ceil(5000/64)
#define TRIW 204800      // padded triangular words per image
#define MASK_PER_IMG ((size_t)TRIW * 8)   // 1,638,400 B
#define GSTRIDE 32       // gcnt padding: 32 u32 = 128 B per image

// Workspace layout (bytes). Boxes live at the front; hist/cut/gcnt/keys are
// DEAD after k_sortdecode, so the mask region overlaps them.
#define OFF_SC    ((size_t)0)
#define OFF_X1    (OFF_SC + 320000)
#define OFF_Y1    (OFF_X1 + 320000)
#define OFF_X2    (OFF_Y1 + 320000)
#define OFF_Y2    (OFF_X2 + 320000)
#define OFF_AREA  (OFF_Y2 + 320000)       // ends at 1,920,000
#define OFF_MASK  ((size_t)1920000)
#define OFF_HIST  ((size_t)1920000)       // overlaps mask (dead before k_mask)
#define OFF_CUT   (OFF_HIST + 65536)      // hist = 16*1024*4 = 65536 B
#define OFF_GCNT  (OFF_CUT + 64)
#define OFF_KEYS  (OFF_GCNT + 2048)

__device__ __forceinline__ unsigned f2ord(float f) {
    unsigned u = __float_as_uint(f);
    return (u & 0x80000000u) ? ~u : (u | 0x80000000u);
}
__device__ __forceinline__ float ord2f(unsigned o) {
    unsigned u = (o & 0x80000000u) ? (o ^ 0x80000000u) : ~o;
    return __uint_as_float(u);
}
// padded row stride (words) of 64-row block t (even)
__device__ __forceinline__ int spad(int t) { int s = NWORDS - t; return s + (s & 1); }
// word offset of block t's slab within an image's padded triangular mask
__device__ __forceinline__ int tri_base_pad(int t) {
    int A = NWORDS - t;                       // 79-t
    int S = A * (A + 1) / 2 + ((A + 1) >> 1); // sum_{a=1..A} ceil_even(a)
    return 64 * (3200 - S);                   // 3200 = S(79)
}

// K1: per-image histogram over the 1024-bucket window in LDS, then one
// contiguous atomic merge per block. Valid scores (0.01,1.0) always land in
// [B2BASE, B2BASE+NB2); invalid are skipped (never scanned by k_cutoff).
__global__ void __launch_bounds__(256) k_hist(const float* __restrict__ conf,
                                              unsigned* __restrict__ hist) {
    __shared__ unsigned lh[NB2];
    int img = blockIdx.y;
    for (int i = threadIdx.x; i < NB2; i += 256) lh[i] = 0;
    __syncthreads();
    const float4* src = (const float4*)(conf + (size_t)img * PNUM * 2);
    int stride = gridDim.x * 256;
    for (int q = blockIdx.x * 256 + threadIdx.x; q < HPNUM; q += stride) {
        float4 v = src[q];
        if (v.y > 0.01f) atomicAdd(&lh[(f2ord(v.y) >> 16) - B2BASE], 1u);
        if (v.w > 0.01f) atomicAdd(&lh[(f2ord(v.w) >> 16) - B2BASE], 1u);
    }
    __syncthreads();
    unsigned* h = hist + (size_t)img * NB2;
    for (int i = threadIdx.x; i < NB2; i += 256) {
        unsigned c = lh[i];
        if (c) atomicAdd(&h[i], c);
    }
}

// K2: find cutoff (absolute 16-bit bucket) so count(bucket >= cut) >= TOPK
__global__ void __launch_bounds__(256) k_cutoff(const unsigned* __restrict__ hist,
                                                unsigned* __restrict__ cut) {
    __shared__ unsigned csum[256];
    int img = blockIdx.x;
    int t = threadIdx.x;
    const unsigned* h = hist + (size_t)img * NB2;
    unsigned s = 0;
    for (int b = 0; b < 4; ++b) s += h[t * 4 + b];
    csum[t] = s;
    __syncthreads();
    if (t == 0) {
        unsigned acc = 0, before = 0;
        int c = -1;
        for (int cc = 255; cc >= 0; --cc) {
            if (acc + csum[cc] >= (unsigned)TOPK) { c = cc; before = acc; break; }
            acc += csum[cc];
        }
        unsigned cutb = B2BASE;            // fallback: take all valid
        if (c >= 0) {
            unsigned s2 = before;
            cutb = B2BASE + (unsigned)c * 4u;
            for (int b = c * 4 + 3; b >= c * 4; --b) {
                s2 += h[b];
                if (s2 >= (unsigned)TOPK) { cutb = B2BASE + (unsigned)b; break; }
            }
        }
        cut[img] = cutb;
    }
}

// K3: gather candidate keys (ord<<32)|~p for buckets >= cutoff.
// Block-aggregated position allocation: ONE atomicAdd per block to a 128B-
// padded counter. Buffer order is irrelevant (keys get fully sorted).
__global__ void __launch_bounds__(256) k_gather(
        const float* __restrict__ conf, const unsigned* __restrict__ cut,
        unsigned* __restrict__ gcnt, unsigned long long* __restrict__ keys) {
    __shared__ unsigned wbase[4];
    __shared__ unsigned bbase;
    int q = blockIdx.x * 256 + threadIdx.x;
    int img = blockIdx.y;
    int lane = threadIdx.x & 63, wid = threadIdx.x >> 6;
    unsigned cutb = cut[img];
    bool c0 = false, c1 = false;
    unsigned o0 = 0, o1 = 0;
    int p0 = 0, p1 = 0;
    if (q < HPNUM) {
        float4 v = ((const float4*)(conf + (size_t)img * PNUM * 2))[q];
        p0 = 2 * q; p1 = 2 * q + 1;
        if (v.y > 0.01f) { o0 = f2ord(v.y); c0 = (o0 >> 16) >= cutb; }
        if (v.w > 0.01f) { o1 = f2ord(v.w); c1 = (o1 >> 16) >= cutb; }
    }
    unsigned long long b0 = __ballot(c0), b1 = __ballot(c1);
    if (lane == 0) wbase[wid] = (unsigned)(__popcll(b0) + __popcll(b1));
    __syncthreads();
    if (threadIdx.x == 0) {
        unsigned t0 = wbase[0], t1 = wbase[1], t2 = wbase[2], t3 = wbase[3];
        unsigned tot = t0 + t1 + t2 + t3;
        unsigned base = tot ? atomicAdd(&gcnt[(size_t)img * GSTRIDE], tot) : 0u;
        bbase = base;
        wbase[0] = 0; wbase[1] = t0; wbase[2] = t0 + t1; wbase[3] = t0 + t1 + t2;
    }
    __syncthreads();
    unsigned mybase = bbase + wbase[wid];
    unsigned long long lt = (lane == 0) ? 0ull : ((1ull << lane) - 1ull);
    if (c0) {
        unsigned pos = mybase + (unsigned)__popcll(b0 & lt);
        if (pos < (unsigned)CAP)
            keys[(size_t)img * CAP + pos] =
                ((unsigned long long)o0 << 32) | (unsigned)(~(unsigned)p0);
    }
    if (c1) {
        unsigned pos = mybase + (unsigned)__popcll(b0) + (unsigned)__popcll(b1 & lt);
        if (pos < (unsigned)CAP)
            keys[(size_t)img * CAP + pos] =
                ((unsigned long long)o1 << 32) | (unsigned)(~(unsigned)p1);
    }
}

// K4: per-image bitonic sort (descending) of up to CAP keys; decode top-5000 boxes
__global__ void __launch_bounds__(1024) k_sortdecode(
        const unsigned long long* __restrict__ keys, const unsigned* __restrict__ gcnt,
        const float* __restrict__ loc, const float* __restrict__ pri,
        float* __restrict__ SC, float* __restrict__ X1, float* __restrict__ Y1,
        float* __restrict__ X2, float* __restrict__ Y2, float* __restrict__ AREA) {
    __shared__ unsigned long long sk[CAP];
    int img = blockIdx.x;
    int tid = threadIdx.x;
    int N = (int)min(gcnt[(size_t)img * GSTRIDE], (unsigned)CAP);
    for (int i = tid; i < CAP; i += 1024)
        sk[i] = (i < N) ? keys[(size_t)img * CAP + i] : 0ull;
    __syncthreads();
    for (int k = 2; k <= CAP; k <<= 1) {
        for (int j = k >> 1; j > 0; j >>= 1) {
            for (int i = tid; i < CAP; i += 1024) {
                int p2 = i ^ j;
                if (p2 > i) {
                    unsigned long long a = sk[i], b = sk[p2];
                    bool descBlock = ((i & k) == 0);
                    bool doSwap = descBlock ? (a < b) : (a > b);
                    if (doSwap) { sk[i] = b; sk[p2] = a; }
                }
            }
            __syncthreads();
        }
    }
    for (int r = tid; r < TOPK; r += 1024) {
        unsigned long long key = sk[r];
        size_t o = (size_t)img * TOPK + r;
        if (key != 0ull) {
            unsigned ordv = (unsigned)(key >> 32);
            float s = ord2f(ordv);
            unsigned p = ~(unsigned)(key & 0xFFFFFFFFull);
            const float* lp = loc + ((size_t)img * PNUM + p) * 4;
            const float* pp = pri + (size_t)p * 4;
            float lx = lp[0], ly = lp[1], lw = lp[2], lh = lp[3];
            float px = pp[0], py = pp[1], pw = pp[2], ph = pp[3];
            float cx = px + (lx * 0.1f) * pw;
            float cy = py + (ly * 0.1f) * ph;
            float w = pw * expf(lw * 0.2f);
            float h = ph * expf(lh * 0.2f);
            float x1 = cx - w * 0.5f;
            float y1 = cy - h * 0.5f;
            float x2 = x1 + w;
            float y2 = y1 + h;
            SC[o] = s; X1[o] = x1; Y1[o] = y1; X2[o] = x2; Y2[o] = y2;
            AREA[o] = (x2 - x1) * (y2 - y1);
        } else {
            SC[o] = -1.0f; X1[o] = 0.f; Y1[o] = 0.f; X2[o] = 0.f; Y2[o] = 0.f;
            AREA[o] = 0.f;
        }
    }
}

// K5a: padded-triangular suppression mask. Row i (block t=i>>6) stores words
// w in [t,79) at g*TRIW + tri_base_pad(t) + (i&63)*spad(t) + (w-t).
// Bit jj of word w = 1 iff row i (valid) suppresses j=w*64+jj (j>i, iou>0.3).
__global__ void __launch_bounds__(256) k_mask(
        const float* __restrict__ SC, const float* __restrict__ X1,
        const float* __restrict__ Y1, const float* __restrict__ X2,
        const float* __restrict__ Y2, const float* __restrict__ AREA,
        unsigned long long* __restrict__ mask, int img0) {
    int g = blockIdx.z;
    int cb = blockIdx.y;
    int bx = blockIdx.x;
    if ((cb + 1) * 64 <= bx * 256) return;   // whole block strictly sub-diagonal
    __shared__ float cx1[64], cy1[64], cx2[64], cy2[64], car[64];
    int img = img0 + g;
    int i = bx * 256 + threadIdx.x;
    int t = threadIdx.x;
    size_t ib = (size_t)img * TOPK;
    if (t < 64) {
        int j = cb * 64 + t;
        if (j < TOPK) {
            cx1[t] = X1[ib + j]; cy1[t] = Y1[ib + j];
            cx2[t] = X2[ib + j]; cy2[t] = Y2[ib + j];
            car[t] = AREA[ib + j];
        } else {
            cx1[t] = 0.f; cy1[t] = 0.f; cx2[t] = 0.f; cy2[t] = 0.f; car[t] = 0.f;
        }
    }
    __syncthreads();
    if (i >= TOPK) return;
    int ti = i >> 6;
    if (cb < ti) return;                     // sub-diagonal word: not stored
    unsigned long long w = 0;
    float vi = SC[ib + i];
    if (vi > 0.01f) {
        float rx1 = X1[ib + i], ry1 = Y1[ib + i];
        float rx2 = X2[ib + i], ry2 = Y2[ib + i];
        float ra = AREA[ib + i];
        #pragma unroll 8
        for (int jj = 0; jj < 64; ++jj) {
            int j = cb * 64 + jj;
            if (j <= i || j >= TOPK) continue;
            float iw = fmaxf(fminf(rx2, cx2[jj]) - fmaxf(rx1, cx1[jj]), 0.0f);
            float ih = fmaxf(fminf(ry2, cy2[jj]) - fmaxf(ry1, cy1[jj]), 0.0f);
            float inter = iw * ih;
            float iou = inter / (car[jj] + ra - inter);  // (area_j + area_i) - inter
            if (iou > 0.3f) w |= (1ull << jj);
        }
    }
    mask[(size_t)g * TRIW + (size_t)tri_base_pad(ti)
         + (size_t)(i & 63) * spad(ti) + (cb - ti)] = w;
}

// K5b: blocked greedy scan, fully cooperative. Per tile t:
//  A) all 256 threads preload the slab into VGPRs (coalesced, no LDS staging)
//  B) wave 0 folds previous tile's partial ORs into register-resident rem,
//     resolves tile t via sparse ballot fast-path + short shfl chain
//  C) all threads fold their kept-row values -> prem[wave][col] in LDS
// One block per image.
__global__ void __launch_bounds__(256) k_scan4(
        const float* __restrict__ SC, const float* __restrict__ X1,
        const float* __restrict__ Y1, const float* __restrict__ X2,
        const float* __restrict__ Y2,
        const unsigned long long* __restrict__ mask, float* __restrict__ out, int img0) {
    __shared__ unsigned long long prem[4][80];
    __shared__ unsigned long long keepw[80];
    __shared__ unsigned pfx[80];
    __shared__ unsigned long long keepm_sh;
    int g = blockIdx.x;
    int img = img0 + g;
    int tid = threadIdx.x;
    int l = tid & 63;
    int wid = tid >> 6;
    size_t ib = (size_t)img * TOPK;
    const float* sc = SC + ib;
    const unsigned long long* mimg = mask + (size_t)g * TRIW;

    // wave-0 lane l owns removed-words l (rem0) and 64+l (rem1, l<15)
    unsigned long long rem0 = ~0ull, rem1 = ~0ull;
    if (wid == 0) {
        for (int w = 0; w < NWORDS; ++w) {
            int row = w * 64 + l;
            bool valid = (row < TOPK) && (sc[row] > 0.01f);
            unsigned long long b = __ballot(valid);
            if (l == w) rem0 = ~b;
            if (l == w - 64) rem1 = ~b;
        }
    }
    __syncthreads();

    for (int t = 0; t < NWORDS; ++t) {
        int s = NWORDS - t;
        int sp = spad(t);
        const unsigned long long* base = mimg + tri_base_pad(t);
        // A: preload. thread (wid,l): rows wid*16..+15, cols l and 64+l.
        bool a0 = (l < s);
        bool a1 = (64 + l < s);
        unsigned long long diag = 0;
        if (wid == 0) diag = base[(size_t)l * sp];
        unsigned long long v0[16], v1[16];
        #pragma unroll
        for (int r = 0; r < 16; ++r) {
            int b = wid * 16 + r;
            v0[r] = a0 ? base[(size_t)b * sp + l] : 0ull;
            v1[r] = a1 ? base[(size_t)b * sp + 64 + l] : 0ull;
        }
        // B: wave 0 folds prev prem, then resolves tile t
        if (wid == 0) {
            if (t > 0) {
                int tp = t - 1;
                int c0 = l - tp;
                if (c0 >= 0)
                    rem0 |= prem[0][c0] | prem[1][c0] | prem[2][c0] | prem[3][c0];
                if (l < 15) {
                    int c1 = 64 + l - tp;
                    if (c1 >= 0)
                        rem1 |= prem[0][c1] | prem[1][c1] | prem[2][c1] | prem[3][c1];
                }
            }
            unsigned long long remT = (t < 64) ? __shfl(rem0, t, 64)
                                               : __shfl(rem1, t - 64, 64);
            unsigned long long aliveInit = ~remT;
            bool meAlive = ((aliveInit >> l) & 1ull) != 0ull;
            unsigned long long dEff = diag & aliveInit;
            unsigned long long sup = __ballot(meAlive && (dEff != 0ull));
            unsigned long long removed = remT;
            while (sup) {                       // usually empty or 1-3 rows
                int i = __builtin_ctzll(sup);
                sup &= sup - 1;
                if (!((removed >> i) & 1ull)) {
                    unsigned long long di = __shfl(diag, i, 64);
                    removed |= di;              // di only has bits > i
                    sup &= ~di;
                }
            }
            unsigned long long keepm = ~removed;
            if (l == 0) { keepw[t] = keepm; keepm_sh = keepm; }
        }
        __syncthreads();
        // C: fold kept rows into per-wave partials
        unsigned long long keepm = keepm_sh;
        unsigned long long acc0 = 0, acc1 = 0;
        #pragma unroll
        for (int r = 0; r < 16; ++r) {
            int b = wid * 16 + r;
            if ((keepm >> b) & 1ull) { acc0 |= v0[r]; acc1 |= v1[r]; }
        }
        if (a0) prem[wid][l] = acc0;
        if (a1) prem[wid][64 + l] = acc1;
        __syncthreads();
    }

    if (tid == 0) {
        unsigned acc = 0;
        for (int w = 0; w < NWORDS; ++w) { pfx[w] = acc; acc += (unsigned)__popcll(keepw[w]); }
    }
    __syncthreads();

    const float* x1 = X1 + ib; const float* y1 = Y1 + ib;
    const float* x2 = X2 + ib; const float* y2 = Y2 + ib;
    float* op = out + (((size_t)img * 2) + 1) * TOPK * 5;
    for (int w = wid; w < NWORDS; w += 4) {
        unsigned long long kw = keepw[w];
        if (!kw) continue;
        int row = w * 64 + l;
        if ((kw >> l) & 1ull) {
            int rank = (int)pfx[w] + (int)__popcll(kw & ((1ull << l) - 1ull));
            float* r = op + (size_t)rank * 5;
            r[0] = sc[row]; r[1] = x1[row]; r[2] = y1[row];
            r[3] = x2[row]; r[4] = y2[row];
        }
    }
}

extern "C" void kernel_launch(void* const* d_in, const int* in_sizes, int n_in,
                              void* d_out, int out_size, void* d_ws, size_t ws_size,
                              hipStream_t stream) {
    (void)in_sizes; (void)n_in;
    const float* loc  = (const float*)d_in[0];   // (16, 136500, 4)
    const float* conf = (const float*)d_in[1];   // (16*136500, 2)
    const float* pri  = (const float*)d_in[2];   // (136500, 4)
    float* out = (float*)d_out;                  // (16, 2, 5000, 5)
    char* ws = (char*)d_ws;

    float* SC   = (float*)(ws + OFF_SC);
    float* X1   = (float*)(ws + OFF_X1);
    float* Y1   = (float*)(ws + OFF_Y1);
    float* X2   = (float*)(ws + OFF_X2);
    float* Y2   = (float*)(ws + OFF_Y2);
    float* AREA = (float*)(ws + OFF_AREA);
    unsigned* hist = (unsigned*)(ws + OFF_HIST);
    unsigned* cut  = (unsigned*)(ws + OFF_CUT);
    unsigned* gcnt = (unsigned*)(ws + OFF_GCNT);
    unsigned long long* keys = (unsigned long long*)(ws + OFF_KEYS);
    unsigned long long* mask = (unsigned long long*)(ws + OFF_MASK);

    hipMemsetAsync(d_out, 0, (size_t)out_size * sizeof(float), stream);
    hipMemsetAsync(ws + OFF_HIST, 0, 65536 + 64 + 2048, stream); // hist+cut+gcnt

    dim3 gh1(16, BNUM);                          // 16 grid-stride blocks/image
    k_hist<<<gh1, 256, 0, stream>>>(conf, hist);
    k_cutoff<<<BNUM, 256, 0, stream>>>(hist, cut);
    dim3 gh2((HPNUM + 255) / 256, BNUM);
    k_gather<<<gh2, 256, 0, stream>>>(conf, cut, gcnt, keys);
    k_sortdecode<<<BNUM, 1024, 0, stream>>>(keys, gcnt, loc, pri, SC, X1, Y1, X2, Y2, AREA);
    // hist/keys region now dead; mask may overwrite it.

    size_t avail = (ws_size > OFF_MASK) ? ws_size - OFF_MASK : 0;
    int gmax = (int)(avail / MASK_PER_IMG);
    if (gmax < 1) gmax = 1;
    if (gmax > BNUM) gmax = BNUM;
    int passes = (BNUM + gmax - 1) / gmax;
    int geach = (BNUM + passes - 1) / passes;   // even split across passes
    for (int i0 = 0; i0 < BNUM; i0 += geach) {
        int G = (BNUM - i0 < geach) ? (BNUM - i0) : geach;
        dim3 mg((TOPK + 255) / 256, NWORDS, G);
        k_mask<<<mg, 256, 0, stream>>>(SC, X1, Y1, X2, Y2, AREA, mask, i0);
        k_scan4<<<G, 256, 0, stream>>>(SC, X1, Y1, X2, Y2, mask, out, i0);
    }
}

// Round 8
// 551.956 us; speedup vs baseline: 3.1523x; 1.0087x over previous
//
#include <hip/hip_runtime.h>
#include <math.h>

#pragma clang fp contract(off)

// Problem constants (match reference)
#define PNUM 136500      // sum of f*f
#define HPNUM 68250      // PNUM/2 (exact)
#define BNUM 16
#define TOPK 5000
#define CAP 8192         // candidate capacity per image (power of 2 for bitonic)
#define NB2 1024         // histogram window buckets (covers ord16 of (0.01, 1.0))
#define B2BASE 0xBC00u   // window base: f2ord(0.01)>>16 = 0xBC23 >= 0xBC00
#define NWORDS 79        // ceil(5000/64)
#define TRIW 202240      // triangular words per image: 64 * (79+78+...+1)
#define MASK_PER_IMG ((size_t)TRIW * 8)   // 1,617,920 B
#define GSTRIDE 32       // gcnt padding: 32 u32 = 128 B per image

// Workspace layout (bytes). Boxes live at the front; hist/cut/gcnt/keys are
// DEAD after k_sortdecode, so the mask region overlaps them.
#define OFF_SC    ((size_t)0)
#define OFF_X1    (OFF_SC + 320000)
#define OFF_Y1    (OFF_X1 + 320000)
#define OFF_X2    (OFF_Y1 + 320000)
#define OFF_Y2    (OFF_X2 + 320000)
#define OFF_AREA  (OFF_Y2 + 320000)       // ends at 1,920,000
#define OFF_MASK  ((size_t)1920000)
#define OFF_HIST  ((size_t)1920000)       // overlaps mask (dead before k_mask)
#define OFF_CUT   (OFF_HIST + 65536)      // hist = 16*1024*4 = 65536 B
#define OFF_GCNT  (OFF_CUT + 64)
#define OFF_KEYS  (OFF_GCNT + 2048)

__device__ __forceinline__ unsigned f2ord(float f) {
    unsigned u = __float_as_uint(f);
    return (u & 0x80000000u) ? ~u : (u | 0x80000000u);
}
__device__ __forceinline__ float ord2f(unsigned o) {
    unsigned u = (o & 0x80000000u) ? (o ^ 0x80000000u) : ~o;
    return __uint_as_float(u);
}
// word offset of block t's slab within an image's triangular mask.
// Slab layout is TRANSPOSED: word w (t<=w<79), row r (0..63) at
// tri_base2(t) + (w-t)*64 + r  -> wave stores (64 rows, same word) coalesce.
__device__ __forceinline__ int tri_base2(int t) {
    return 64 * (79 * t - ((t * (t - 1)) >> 1));
}

// K1: per-image histogram over the 1024-bucket window in LDS, then one
// contiguous atomic merge per block. Valid scores (0.01,1.0) always land in
// [B2BASE, B2BASE+NB2); invalid are skipped (never scanned by k_cutoff).
__global__ void __launch_bounds__(256) k_hist(const float* __restrict__ conf,
                                              unsigned* __restrict__ hist) {
    __shared__ unsigned lh[NB2];
    int img = blockIdx.y;
    for (int i = threadIdx.x; i < NB2; i += 256) lh[i] = 0;
    __syncthreads();
    const float4* src = (const float4*)(conf + (size_t)img * PNUM * 2);
    int stride = gridDim.x * 256;
    for (int q = blockIdx.x * 256 + threadIdx.x; q < HPNUM; q += stride) {
        float4 v = src[q];
        if (v.y > 0.01f) atomicAdd(&lh[(f2ord(v.y) >> 16) - B2BASE], 1u);
        if (v.w > 0.01f) atomicAdd(&lh[(f2ord(v.w) >> 16) - B2BASE], 1u);
    }
    __syncthreads();
    unsigned* h = hist + (size_t)img * NB2;
    for (int i = threadIdx.x; i < NB2; i += 256) {
        unsigned c = lh[i];
        if (c) atomicAdd(&h[i], c);
    }
}

// K2: find cutoff (absolute 16-bit bucket) so count(bucket >= cut) >= TOPK
__global__ void __launch_bounds__(256) k_cutoff(const unsigned* __restrict__ hist,
                                                unsigned* __restrict__ cut) {
    __shared__ unsigned csum[256];
    int img = blockIdx.x;
    int t = threadIdx.x;
    const unsigned* h = hist + (size_t)img * NB2;
    unsigned s = 0;
    for (int b = 0; b < 4; ++b) s += h[t * 4 + b];
    csum[t] = s;
    __syncthreads();
    if (t == 0) {
        unsigned acc = 0, before = 0;
        int c = -1;
        for (int cc = 255; cc >= 0; --cc) {
            if (acc + csum[cc] >= (unsigned)TOPK) { c = cc; before = acc; break; }
            acc += csum[cc];
        }
        unsigned cutb = B2BASE;            // fallback: take all valid
        if (c >= 0) {
            unsigned s2 = before;
            cutb = B2BASE + (unsigned)c * 4u;
            for (int b = c * 4 + 3; b >= c * 4; --b) {
                s2 += h[b];
                if (s2 >= (unsigned)TOPK) { cutb = B2BASE + (unsigned)b; break; }
            }
        }
        cut[img] = cutb;
    }
}

// K3: gather candidate keys (ord<<32)|~p for buckets >= cutoff.
// Block-aggregated position allocation: ONE atomicAdd per block to a 128B-
// padded counter. Buffer order is irrelevant (keys get fully sorted).
__global__ void __launch_bounds__(256) k_gather(
        const float* __restrict__ conf, const unsigned* __restrict__ cut,
        unsigned* __restrict__ gcnt, unsigned long long* __restrict__ keys) {
    __shared__ unsigned wbase[4];
    __shared__ unsigned bbase;
    int q = blockIdx.x * 256 + threadIdx.x;
    int img = blockIdx.y;
    int lane = threadIdx.x & 63, wid = threadIdx.x >> 6;
    unsigned cutb = cut[img];
    bool c0 = false, c1 = false;
    unsigned o0 = 0, o1 = 0;
    int p0 = 0, p1 = 0;
    if (q < HPNUM) {
        float4 v = ((const float4*)(conf + (size_t)img * PNUM * 2))[q];
        p0 = 2 * q; p1 = 2 * q + 1;
        if (v.y > 0.01f) { o0 = f2ord(v.y); c0 = (o0 >> 16) >= cutb; }
        if (v.w > 0.01f) { o1 = f2ord(v.w); c1 = (o1 >> 16) >= cutb; }
    }
    unsigned long long b0 = __ballot(c0), b1 = __ballot(c1);
    if (lane == 0) wbase[wid] = (unsigned)(__popcll(b0) + __popcll(b1));
    __syncthreads();
    if (threadIdx.x == 0) {
        unsigned t0 = wbase[0], t1 = wbase[1], t2 = wbase[2], t3 = wbase[3];
        unsigned tot = t0 + t1 + t2 + t3;
        unsigned base = tot ? atomicAdd(&gcnt[(size_t)img * GSTRIDE], tot) : 0u;
        bbase = base;
        wbase[0] = 0; wbase[1] = t0; wbase[2] = t0 + t1; wbase[3] = t0 + t1 + t2;
    }
    __syncthreads();
    unsigned mybase = bbase + wbase[wid];
    unsigned long long lt = (lane == 0) ? 0ull : ((1ull << lane) - 1ull);
    if (c0) {
        unsigned pos = mybase + (unsigned)__popcll(b0 & lt);
        if (pos < (unsigned)CAP)
            keys[(size_t)img * CAP + pos] =
                ((unsigned long long)o0 << 32) | (unsigned)(~(unsigned)p0);
    }
    if (c1) {
        unsigned pos = mybase + (unsigned)__popcll(b0) + (unsigned)__popcll(b1 & lt);
        if (pos < (unsigned)CAP)
            keys[(size_t)img * CAP + pos] =
                ((unsigned long long)o1 << 32) | (unsigned)(~(unsigned)p1);
    }
}

// K4: per-image bitonic sort (descending) of up to CAP keys; decode top-5000 boxes
__global__ void __launch_bounds__(1024) k_sortdecode(
        const unsigned long long* __restrict__ keys, const unsigned* __restrict__ gcnt,
        const float* __restrict__ loc, const float* __restrict__ pri,
        float* __restrict__ SC, float* __restrict__ X1, float* __restrict__ Y1,
        float* __restrict__ X2, float* __restrict__ Y2, float* __restrict__ AREA) {
    __shared__ unsigned long long sk[CAP];
    int img = blockIdx.x;
    int tid = threadIdx.x;
    int N = (int)min(gcnt[(size_t)img * GSTRIDE], (unsigned)CAP);
    for (int i = tid; i < CAP; i += 1024)
        sk[i] = (i < N) ? keys[(size_t)img * CAP + i] : 0ull;
    __syncthreads();
    for (int k = 2; k <= CAP; k <<= 1) {
        for (int j = k >> 1; j > 0; j >>= 1) {
            for (int i = tid; i < CAP; i += 1024) {
                int p2 = i ^ j;
                if (p2 > i) {
                    unsigned long long a = sk[i], b = sk[p2];
                    bool descBlock = ((i & k) == 0);
                    bool doSwap = descBlock ? (a < b) : (a > b);
                    if (doSwap) { sk[i] = b; sk[p2] = a; }
                }
            }
            __syncthreads();
        }
    }
    for (int r = tid; r < TOPK; r += 1024) {
        unsigned long long key = sk[r];
        size_t o = (size_t)img * TOPK + r;
        if (key != 0ull) {
            unsigned ordv = (unsigned)(key >> 32);
            float s = ord2f(ordv);
            unsigned p = ~(unsigned)(key & 0xFFFFFFFFull);
            const float* lp = loc + ((size_t)img * PNUM + p) * 4;
            const float* pp = pri + (size_t)p * 4;
            float lx = lp[0], ly = lp[1], lw = lp[2], lh = lp[3];
            float px = pp[0], py = pp[1], pw = pp[2], ph = pp[3];
            float cx = px + (lx * 0.1f) * pw;
            float cy = py + (ly * 0.1f) * ph;
            float w = pw * expf(lw * 0.2f);
            float h = ph * expf(lh * 0.2f);
            float x1 = cx - w * 0.5f;
            float y1 = cy - h * 0.5f;
            float x2 = x1 + w;
            float y2 = y1 + h;
            SC[o] = s; X1[o] = x1; Y1[o] = y1; X2[o] = x2; Y2[o] = y2;
            AREA[o] = (x2 - x1) * (y2 - y1);
        } else {
            SC[o] = -1.0f; X1[o] = 0.f; Y1[o] = 0.f; X2[o] = 0.f; Y2[o] = 0.f;
            AREA[o] = 0.f;
        }
    }
}

// K5a: transposed triangular suppression mask. Bit jj of word w (row i,
// block t=i>>6) = 1 iff row i (valid) suppresses j=w*64+jj (j>i, iou>0.3).
// Early-out: overlap test (6 ops) gates the IEEE division (exact: no overlap
// => inter=0 => iou=0 fails the >0.3 test; areas are strictly positive).
__global__ void __launch_bounds__(256) k_mask(
        const float* __restrict__ SC, const float* __restrict__ X1,
        const float* __restrict__ Y1, const float* __restrict__ X2,
        const float* __restrict__ Y2, const float* __restrict__ AREA,
        unsigned long long* __restrict__ mask, int img0) {
    int g = blockIdx.z;
    int cb = blockIdx.y;
    int bx = blockIdx.x;
    if ((cb + 1) * 64 <= bx * 256) return;   // whole block strictly sub-diagonal
    __shared__ float cx1[64], cy1[64], cx2[64], cy2[64], car[64];
    int img = img0 + g;
    int i = bx * 256 + threadIdx.x;
    int t = threadIdx.x;
    size_t ib = (size_t)img * TOPK;
    if (t < 64) {
        int j = cb * 64 + t;
        if (j < TOPK) {
            cx1[t] = X1[ib + j]; cy1[t] = Y1[ib + j];
            cx2[t] = X2[ib + j]; cy2[t] = Y2[ib + j];
            car[t] = AREA[ib + j];
        } else {
            cx1[t] = 0.f; cy1[t] = 0.f; cx2[t] = 0.f; cy2[t] = 0.f; car[t] = 0.f;
        }
    }
    __syncthreads();
    if (i >= TOPK) return;
    int ti = i >> 6;
    if (cb < ti) return;                     // sub-diagonal word: not stored
    unsigned long long w = 0;
    float vi = SC[ib + i];
    if (vi > 0.01f) {
        float rx1 = X1[ib + i], ry1 = Y1[ib + i];
        float rx2 = X2[ib + i], ry2 = Y2[ib + i];
        float ra = AREA[ib + i];
        #pragma unroll 4
        for (int jj = 0; jj < 64; ++jj) {
            int j = cb * 64 + jj;
            if (j <= i || j >= TOPK) continue;
            float dx = fminf(rx2, cx2[jj]) - fmaxf(rx1, cx1[jj]);
            float dy = fminf(ry2, cy2[jj]) - fmaxf(ry1, cy1[jj]);
            if (dx > 0.0f && dy > 0.0f) {
                float inter = dx * dy;
                float iou = inter / (car[jj] + ra - inter);  // (area_j+area_i)-inter
                if (iou > 0.3f) w |= (1ull << jj);
            }
        }
    }
    mask[(size_t)g * TRIW + (size_t)tri_base2(ti)
         + (size_t)(cb - ti) * 64 + (i & 63)] = w;
}

// K5b: blocked greedy scan, fully cooperative. Per tile t:
//  A) all 256 threads preload the slab into VGPRs (coalesced, no LDS staging)
//  B) wave 0 folds previous tile's partial ORs into register-resident rem,
//     resolves tile t via sparse ballot fast-path + short shfl chain
//  C) all threads fold their kept-row values -> prem[wave][col] in LDS
// One block per image. Slab layout transposed: word-major, rows contiguous.
__global__ void __launch_bounds__(256) k_scan4(
        const float* __restrict__ SC, const float* __restrict__ X1,
        const float* __restrict__ Y1, const float* __restrict__ X2,
        const float* __restrict__ Y2,
        const unsigned long long* __restrict__ mask, float* __restrict__ out, int img0) {
    __shared__ unsigned long long prem[4][80];
    __shared__ unsigned long long keepw[80];
    __shared__ unsigned pfx[80];
    __shared__ unsigned long long keepm_sh;
    int g = blockIdx.x;
    int img = img0 + g;
    int tid = threadIdx.x;
    int l = tid & 63;
    int wid = tid >> 6;
    size_t ib = (size_t)img * TOPK;
    const float* sc = SC + ib;
    const unsigned long long* mimg = mask + (size_t)g * TRIW;

    // wave-0 lane l owns removed-words l (rem0) and 64+l (rem1, l<15)
    unsigned long long rem0 = ~0ull, rem1 = ~0ull;
    if (wid == 0) {
        for (int w = 0; w < NWORDS; ++w) {
            int row = w * 64 + l;
            bool valid = (row < TOPK) && (sc[row] > 0.01f);
            unsigned long long b = __ballot(valid);
            if (l == w) rem0 = ~b;
            if (l == w - 64) rem1 = ~b;
        }
    }
    __syncthreads();

    for (int t = 0; t < NWORDS; ++t) {
        int s = NWORDS - t;
        const unsigned long long* base = mimg + tri_base2(t);
        // A: preload. thread (wid,l): rows wid*16..+15, word-cols l and 64+l.
        // Transposed layout: addr = (w-t)*64 + row -> 16 consecutive u64/thread.
        bool a0 = (l < s);
        bool a1 = (64 + l < s);
        unsigned long long diag = 0;
        if (wid == 0) diag = base[l];            // word t, row l (contiguous)
        unsigned long long v0[16], v1[16];
        #pragma unroll
        for (int r = 0; r < 16; ++r) {
            int b = wid * 16 + r;
            v0[r] = a0 ? base[(size_t)l * 64 + b] : 0ull;
            v1[r] = a1 ? base[(size_t)(64 + l) * 64 + b] : 0ull;
        }
        // B: wave 0 folds prev prem, then resolves tile t
        if (wid == 0) {
            if (t > 0) {
                int tp = t - 1;
                int c0 = l - tp;
                if (c0 >= 0)
                    rem0 |= prem[0][c0] | prem[1][c0] | prem[2][c0] | prem[3][c0];
                if (l < 15) {
                    int c1 = 64 + l - tp;
                    if (c1 >= 0)
                        rem1 |= prem[0][c1] | prem[1][c1] | prem[2][c1] | prem[3][c1];
                }
            }
            unsigned long long remT = (t < 64) ? __shfl(rem0, t, 64)
                                               : __shfl(rem1, t - 64, 64);
            unsigned long long aliveInit = ~remT;
            bool meAlive = ((aliveInit >> l) & 1ull) != 0ull;
            unsigned long long dEff = diag & aliveInit;
            unsigned long long sup = __ballot(meAlive && (dEff != 0ull));
            unsigned long long removed = remT;
            while (sup) {                       // usually empty or 1-3 rows
                int i = __builtin_ctzll(sup);
                sup &= sup - 1;
                if (!((removed >> i) & 1ull)) {
                    unsigned long long di = __shfl(diag, i, 64);
                    removed |= di;              // di only has bits > i
                    sup &= ~di;
                }
            }
            unsigned long long keepm = ~removed;
            if (l == 0) { keepw[t] = keepm; keepm_sh = keepm; }
        }
        __syncthreads();
        // C: fold kept rows into per-wave partials
        unsigned long long keepm = keepm_sh;
        unsigned long long acc0 = 0, acc1 = 0;
        #pragma unroll
        for (int r = 0; r < 16; ++r) {
            int b = wid * 16 + r;
            if ((keepm >> b) & 1ull) { acc0 |= v0[r]; acc1 |= v1[r]; }
        }
        if (a0) prem[wid][l] = acc0;
        if (a1) prem[wid][64 + l] = acc1;
        __syncthreads();
    }

    if (tid == 0) {
        unsigned acc = 0;
        for (int w = 0; w < NWORDS; ++w) { pfx[w] = acc; acc += (unsigned)__popcll(keepw[w]); }
    }
    __syncthreads();

    const float* x1 = X1 + ib; const float* y1 = Y1 + ib;
    const float* x2 = X2 + ib; const float* y2 = Y2 + ib;
    float* op = out + (((size_t)img * 2) + 1) * TOPK * 5;
    for (int w = wid; w < NWORDS; w += 4) {
        unsigned long long kw = keepw[w];
        if (!kw) continue;
        int row = w * 64 + l;
        if ((kw >> l) & 1ull) {
            int rank = (int)pfx[w] + (int)__popcll(kw & ((1ull << l) - 1ull));
            float* r = op + (size_t)rank * 5;
            r[0] = sc[row]; r[1] = x1[row]; r[2] = y1[row];
            r[3] = x2[row]; r[4] = y2[row];
        }
    }
}

extern "C" void kernel_launch(void* const* d_in, const int* in_sizes, int n_in,
                              void* d_out, int out_size, void* d_ws, size_t ws_size,
                              hipStream_t stream) {
    (void)in_sizes; (void)n_in;
    const float* loc  = (const float*)d_in[0];   // (16, 136500, 4)
    const float* conf = (const float*)d_in[1];   // (16*136500, 2)
    const float* pri  = (const float*)d_in[2];   // (136500, 4)
    float* out = (float*)d_out;                  // (16, 2, 5000, 5)
    char* ws = (char*)d_ws;

    float* SC   = (float*)(ws + OFF_SC);
    float* X1   = (float*)(ws + OFF_X1);
    float* Y1   = (float*)(ws + OFF_Y1);
    float* X2   = (float*)(ws + OFF_X2);
    float* Y2   = (float*)(ws + OFF_Y2);
    float* AREA = (float*)(ws + OFF_AREA);
    unsigned* hist = (unsigned*)(ws + OFF_HIST);
    unsigned* cut  = (unsigned*)(ws + OFF_CUT);
    unsigned* gcnt = (unsigned*)(ws + OFF_GCNT);
    unsigned long long* keys = (unsigned long long*)(ws + OFF_KEYS);
    unsigned long long* mask = (unsigned long long*)(ws + OFF_MASK);

    hipMemsetAsync(d_out, 0, (size_t)out_size * sizeof(float), stream);
    hipMemsetAsync(ws + OFF_HIST, 0, 65536 + 64 + 2048, stream); // hist+cut+gcnt

    dim3 gh1(16, BNUM);                          // 16 grid-stride blocks/image
    k_hist<<<gh1, 256, 0, stream>>>(conf, hist);
    k_cutoff<<<BNUM, 256, 0, stream>>>(hist, cut);
    dim3 gh2((HPNUM + 255) / 256, BNUM);
    k_gather<<<gh2, 256, 0, stream>>>(conf, cut, gcnt, keys);
    k_sortdecode<<<BNUM, 1024, 0, stream>>>(keys, gcnt, loc, pri, SC, X1, Y1, X2, Y2, AREA);
    // hist/keys region now dead; mask may overwrite it.

    size_t avail = (ws_size > OFF_MASK) ? ws_size - OFF_MASK : 0;
    int gmax = (int)(avail / MASK_PER_IMG);
    if (gmax < 1) gmax = 1;
    if (gmax > BNUM) gmax = BNUM;
    int passes = (BNUM + gmax - 1) / gmax;
    int geach = (BNUM + passes - 1) / passes;   // even split across passes
    for (int i0 = 0; i0 < BNUM; i0 += geach) {
        int G = (BNUM - i0 < geach) ? (BNUM - i0) : geach;
        dim3 mg((TOPK + 255) / 256, NWORDS, G);
        k_mask<<<mg, 256, 0, stream>>>(SC, X1, Y1, X2, Y2, AREA, mask, i0);
        k_scan4<<<G, 256, 0, stream>>>(SC, X1, Y1, X2, Y2, mask, out, i0);
    }
}